// Round 3
// baseline (445.118 us; speedup 1.0000x reference)
//
#include <hip/hip_runtime.h>

#define D 128

typedef unsigned short u16;
typedef unsigned int   u32;
typedef __attribute__((ext_vector_type(8))) short bf16x8;
typedef __attribute__((ext_vector_type(4))) float f32x4;
typedef __attribute__((ext_vector_type(2))) float f32x2;

__device__ __forceinline__ u16 f32_to_bf16(float f) {
    unsigned u = __float_as_uint(f);
    unsigned rounding = 0x7fffu + ((u >> 16) & 1u);   // round-to-nearest-even
    return (u16)((u + rounding) >> 16);
}

__device__ __forceinline__ float bf16_to_f32(u16 s) {
    return __uint_as_float(((unsigned)s) << 16);
}

// -------------------------------------------------------------------------
// Kernel 0: Wt[n][k] = bf16(W[k][n]).  16384 elements, 64 blocks.
// -------------------------------------------------------------------------
__global__ __launch_bounds__(256) void prep_kernel(
    const float* __restrict__ W, u16* __restrict__ Wt)
{
    int idx = blockIdx.x * 256 + threadIdx.x;   // idx = n*128 + k
    int n = idx >> 7;
    int k = idx & 127;
    Wt[idx] = f32_to_bf16(W[k * 128 + n]);
}

// -------------------------------------------------------------------------
// Kernel 1: support = bf16(x @ W + b) via MFMA 16x16x32 bf16.
// Epilogue writes sup in SLICE-MAJOR layout: sup[s][node][16] bf16,
// s = nt (each nt tile is exactly one 16-feature slice). A 128 B cache
// line then holds 4 nodes of ONE slice -> per-XCD L2 working set in the
// spmm gather is N*32 B = 3.2 MB (fits the 4 MB XCD L2).
// -------------------------------------------------------------------------
__global__ __launch_bounds__(256) void gemm_mfma_kernel(
    const float* __restrict__ x, const u16* __restrict__ Wt,
    const float* __restrict__ b, u16* __restrict__ sup, int N)
{
    const int lane = threadIdx.x & 63;
    const int wave = threadIdx.x >> 6;
    const int col  = lane & 15;
    const int quad = lane >> 4;
    const int row0 = blockIdx.x * 64 + wave * 16;
    const int m    = row0 + col;
    const bool mvalid = (m < N);

    f32x4 acc[8];
    #pragma unroll
    for (int nt = 0; nt < 8; ++nt) {
        float bias = b[nt * 16 + col];
        acc[nt][0] = bias; acc[nt][1] = bias;
        acc[nt][2] = bias; acc[nt][3] = bias;
    }

    const float* xrow = x + (size_t)m * D;

    #pragma unroll
    for (int ks = 0; ks < 4; ++ks) {
        const int k0 = ks * 32 + quad * 8;

        float af[8];
        if (mvalid) {
            float4 v0 = *(const float4*)(xrow + k0);
            float4 v1 = *(const float4*)(xrow + k0 + 4);
            af[0] = v0.x; af[1] = v0.y; af[2] = v0.z; af[3] = v0.w;
            af[4] = v1.x; af[5] = v1.y; af[6] = v1.z; af[7] = v1.w;
        } else {
            #pragma unroll
            for (int j = 0; j < 8; ++j) af[j] = 0.f;
        }

        bf16x8 ahi, alo;
        #pragma unroll
        for (int j = 0; j < 8; ++j) {
            u16 h = f32_to_bf16(af[j]);
            float r = af[j] - bf16_to_f32(h);
            ahi[j] = (short)h;
            alo[j] = (short)f32_to_bf16(r);
        }

        #pragma unroll
        for (int nt = 0; nt < 8; ++nt) {
            bf16x8 bfrag = *(const bf16x8*)(Wt + (size_t)(nt * 16 + col) * D + k0);
            acc[nt] = __builtin_amdgcn_mfma_f32_16x16x32_bf16(alo, bfrag, acc[nt], 0, 0, 0);
            acc[nt] = __builtin_amdgcn_mfma_f32_16x16x32_bf16(ahi, bfrag, acc[nt], 0, 0, 0);
        }
    }

    #pragma unroll
    for (int reg = 0; reg < 4; ++reg) {
        int r = row0 + quad * 4 + reg;
        if (r < N) {
            #pragma unroll
            for (int nt = 0; nt < 8; ++nt) {
                // slice-major: slice nt, node r, feature col
                sup[((size_t)nt * N + r) * 16 + col] = f32_to_bf16(acc[nt][reg]);
            }
        }
    }
}

// -------------------------------------------------------------------------
// Kernel 2: row_ptr from sorted edge_dst. rp[n] = lower_bound(edge_dst, n).
// -------------------------------------------------------------------------
__global__ __launch_bounds__(256) void rowptr_kernel(
    const int* __restrict__ edst, int* __restrict__ rp, int E, int N)
{
    int e = blockIdx.x * 256 + threadIdx.x;
    if (e >= E) return;
    int d = edst[e];
    int prev = (e == 0) ? -1 : edst[e - 1];
    for (int n = prev + 1; n <= d; ++n) rp[n] = e;
    if (e == E - 1) {
        for (int n = d + 1; n <= N; ++n) rp[n] = E;
    }
}

// -------------------------------------------------------------------------
// Kernel 3: SpMM with 8-way XCD feature slicing.
//  - slice = blockIdx & 7 -> one slice per XCD (blockIdx%8 round-robins
//    over XCDs; validated by R0's capacity-model-matching fill reduction).
//  - sup is slice-major [8][N][16] bf16: per-XCD gather working set is
//    N*32 B = 3.2 MB < 4 MB XCD L2 -> gathers become L2-resident.
//  - esrc/ew are streamed once per XCD (8x total) with NONTEMPORAL loads
//    so the stream does not evict the resident sup slice; out stores are
//    nontemporal for the same reason.
//  - lane = eg*8 + fo: one global_load_dword gathers 8 edges x 32 B.
//    Two batches (16 edges) in flight per wave for MLP.
//  - epilogue: 3-round shfl_xor reduce over edge-groups, 8 lanes store
//    64 B of out (feats [slice*16, slice*16+16)).
// -------------------------------------------------------------------------
__global__ __launch_bounds__(256) void spmm_kernel(
    const u16* __restrict__ sup, const float* __restrict__ ew,
    const int* __restrict__ esrc, const int* __restrict__ rp,
    float* __restrict__ out, int N)
{
    const int b     = blockIdx.x;
    const int slice = b & 7;
    const int grp   = b >> 3;
    const int wave  = threadIdx.x >> 6;
    const int lane  = threadIdx.x & 63;
    const int node  = grp * 4 + wave;
    if (node >= N) return;

    const int eg = lane >> 3;                    // edge group 0..7
    const int fo = lane & 7;                     // dword within 32 B row

    const int start = __builtin_amdgcn_readfirstlane(rp[node]);
    const int end   = __builtin_amdgcn_readfirstlane(rp[node + 1]);

    const u32* sbase = (const u32*)(sup + (size_t)slice * (size_t)N * 16);

    float acc0 = 0.f, acc1 = 0.f;

    for (int base = start; base < end; base += 64) {
        const int cnt = min(64, end - base);
        const int mi  = base + lane;
        int   sv = 0;
        float wv = 0.f;
        if (mi < end) {
            sv = __builtin_nontemporal_load(esrc + mi);
            wv = __builtin_nontemporal_load(ew + mi);
        }

        for (int i0 = 0; i0 < cnt; i0 += 16) {
            const int idxA = i0 + eg;
            const int idxB = i0 + 8 + eg;
            const int cA = (idxA < cnt) ? idxA : (cnt - 1);
            const int cB = (idxB < cnt) ? idxB : (cnt - 1);
            const int   sA = __shfl(sv, cA);
            const int   sB = __shfl(sv, cB);
            float wA = __shfl(wv, cA);
            float wB = __shfl(wv, cB);
            if (idxA >= cnt) wA = 0.f;
            if (idxB >= cnt) wB = 0.f;

            const u32 uA = sbase[(size_t)(u32)sA * 8 + fo];
            const u32 uB = sbase[(size_t)(u32)sB * 8 + fo];

            acc0 = fmaf(wA, __uint_as_float(uA << 16),         acc0);
            acc1 = fmaf(wA, __uint_as_float(uA & 0xffff0000u), acc1);
            acc0 = fmaf(wB, __uint_as_float(uB << 16),         acc0);
            acc1 = fmaf(wB, __uint_as_float(uB & 0xffff0000u), acc1);
        }
    }

    #pragma unroll
    for (int m = 8; m <= 32; m <<= 1) {
        acc0 += __shfl_xor(acc0, m);
        acc1 += __shfl_xor(acc1, m);
    }

    if (eg == 0) {
        f32x2 o;
        o.x = acc0;
        o.y = acc1;
        f32x2* dst = (f32x2*)(out + (size_t)node * D + slice * 16 + fo * 2);
        __builtin_nontemporal_store(o, dst);
    }
}

extern "C" void kernel_launch(void* const* d_in, const int* in_sizes, int n_in,
                              void* d_out, int out_size, void* d_ws, size_t ws_size,
                              hipStream_t stream) {
    const float* x    = (const float*)d_in[0];
    const float* W    = (const float*)d_in[1];
    const float* b    = (const float*)d_in[2];
    const float* ew   = (const float*)d_in[3];
    const int*   esrc = (const int*)d_in[4];
    const int*   edst = (const int*)d_in[5];
    float* out = (float*)d_out;

    const int N = in_sizes[0] / D;
    const int E = in_sizes[3];

    u16* sup = (u16*)d_ws;                                        // [8][N][16] bf16
    int* rp  = (int*)((char*)d_ws + (size_t)N * D * sizeof(u16)); // N+1 ints
    u16* Wt  = (u16*)((char*)rp + ((size_t)N + 16) * sizeof(int));// 128*128 bf16

    hipLaunchKernelGGL(prep_kernel, dim3(64), dim3(256), 0, stream, W, Wt);
    hipLaunchKernelGGL(gemm_mfma_kernel, dim3((N + 63) / 64), dim3(256), 0, stream,
                       x, Wt, b, sup, N);
    hipLaunchKernelGGL(rowptr_kernel, dim3((E + 255) / 256), dim3(256), 0, stream,
                       edst, rp, E, N);

    int grid_spmm = ((N + 3) / 4) * 8;
    hipLaunchKernelGGL(spmm_kernel, dim3(grid_spmm), dim3(256), 0, stream,
                       sup, ew, esrc, rp, out, N);
}

// Round 5
// 434.771 us; speedup vs baseline: 1.0238x; 1.0238x over previous
//
#include <hip/hip_runtime.h>

#define D 128

typedef unsigned short u16;
typedef unsigned int   u32;
typedef __attribute__((ext_vector_type(8))) short bf16x8;
typedef __attribute__((ext_vector_type(4))) float f32x4;

__device__ __forceinline__ u16 f32_to_bf16(float f) {
    unsigned u = __float_as_uint(f);
    unsigned rounding = 0x7fffu + ((u >> 16) & 1u);   // round-to-nearest-even
    return (u16)((u + rounding) >> 16);
}

__device__ __forceinline__ float bf16_to_f32(u16 s) {
    return __uint_as_float(((unsigned)s) << 16);
}

// Grid-wide barrier without the cooperative API.
// Requires all blocks co-resident: grid = 512 = 2 blocks/CU x 256 CUs,
// guaranteed by __launch_bounds__(256,2) (<=256 VGPR incl. AGPR, LDS=0).
// ctr is zeroed by hipMemsetAsync before the kernel. Agent-scope ACQ_REL
// RMW + ACQUIRE spin emit the L2 writeback/invalidate needed for
// cross-XCD visibility on gfx950.
__device__ __forceinline__ void grid_barrier(int* ctr, int target) {
    __syncthreads();
    if (threadIdx.x == 0) {
        __hip_atomic_fetch_add(ctr, 1, __ATOMIC_ACQ_REL, __HIP_MEMORY_SCOPE_AGENT);
        while (__hip_atomic_load(ctr, __ATOMIC_ACQUIRE, __HIP_MEMORY_SCOPE_AGENT) < target) {
            __builtin_amdgcn_s_sleep(2);
        }
    }
    __syncthreads();
}

// -------------------------------------------------------------------------
// ONE persistent kernel, 512 blocks x 256 threads (2 blocks/CU).
// Phase 0: Wt transpose (prep) + row_ptr build        [independent]
// Phase 1: support = bf16(x @ W + b)  (MFMA)          [needs Wt]
// Phase 2: SpMM gather-accumulate                     [needs sup, rp]
// Self-managed grid barriers replace 3 kernel-launch boundaries.
// Stride 512 % 8 == 0 keeps vb&7 == blockIdx&7, preserving the spmm
// XCD/feature-half mapping per physical block.
// spmm inner loop deepened to 8 outstanding uint4 gathers (64 edges/iter)
// to compensate for lower occupancy (8 waves/CU persistent vs ~24 before).
// -------------------------------------------------------------------------
__global__ __launch_bounds__(256, 2) void fused_kernel(
    const float* __restrict__ x, const float* __restrict__ W,
    const float* __restrict__ b, const float* __restrict__ ew,
    const int* __restrict__ esrc, const int* __restrict__ edst,
    float* __restrict__ out, u16* __restrict__ sup,
    int* __restrict__ rp, u16* __restrict__ Wt,
    int* __restrict__ bar, int N, int E)
{
    const int tid  = threadIdx.x;
    const int nblk = gridDim.x;

    // ---------------- Phase 0a: prep  (Wt[n][k] = bf16(W[k][n])) ----------
    for (int vb = blockIdx.x; vb < 64; vb += nblk) {
        int idx = vb * 256 + tid;            // idx = n*128 + k
        int n = idx >> 7;
        int k = idx & 127;
        Wt[idx] = f32_to_bf16(W[k * 128 + n]);
    }

    // ---------------- Phase 0b: rowptr ------------------------------------
    {
        const int nvb = (E + 255) / 256;
        for (int vb = blockIdx.x; vb < nvb; vb += nblk) {
            int e = vb * 256 + tid;
            if (e < E) {
                int d = edst[e];
                int prev = (e == 0) ? -1 : edst[e - 1];
                for (int n = prev + 1; n <= d; ++n) rp[n] = e;
                if (e == E - 1) {
                    for (int n = d + 1; n <= N; ++n) rp[n] = E;
                }
            }
        }
    }

    grid_barrier(bar, nblk);

    // ---------------- Phase 1: GEMM (support = bf16(x@W + b)) -------------
    {
        const int lane = tid & 63;
        const int wave = tid >> 6;
        const int col  = lane & 15;
        const int quad = lane >> 4;
        const int nvb  = (N + 63) / 64;

        for (int vb = blockIdx.x; vb < nvb; vb += nblk) {
            const int row0 = vb * 64 + wave * 16;
            const int m    = row0 + col;
            const bool mvalid = (m < N);

            f32x4 acc[8];
            #pragma unroll
            for (int nt = 0; nt < 8; ++nt) {
                float bias = b[nt * 16 + col];
                acc[nt][0] = bias; acc[nt][1] = bias;
                acc[nt][2] = bias; acc[nt][3] = bias;
            }

            const float* xrow = x + (size_t)m * D;

            #pragma unroll
            for (int ks = 0; ks < 4; ++ks) {
                const int k0 = ks * 32 + quad * 8;

                float af[8];
                if (mvalid) {
                    float4 v0 = *(const float4*)(xrow + k0);
                    float4 v1 = *(const float4*)(xrow + k0 + 4);
                    af[0] = v0.x; af[1] = v0.y; af[2] = v0.z; af[3] = v0.w;
                    af[4] = v1.x; af[5] = v1.y; af[6] = v1.z; af[7] = v1.w;
                } else {
                    #pragma unroll
                    for (int j = 0; j < 8; ++j) af[j] = 0.f;
                }

                bf16x8 ahi, alo;
                #pragma unroll
                for (int j = 0; j < 8; ++j) {
                    u16 h = f32_to_bf16(af[j]);
                    float r = af[j] - bf16_to_f32(h);
                    ahi[j] = (short)h;
                    alo[j] = (short)f32_to_bf16(r);
                }

                #pragma unroll
                for (int nt = 0; nt < 8; ++nt) {
                    bf16x8 bfrag = *(const bf16x8*)(Wt + (size_t)(nt * 16 + col) * D + k0);
                    acc[nt] = __builtin_amdgcn_mfma_f32_16x16x32_bf16(alo, bfrag, acc[nt], 0, 0, 0);
                    acc[nt] = __builtin_amdgcn_mfma_f32_16x16x32_bf16(ahi, bfrag, acc[nt], 0, 0, 0);
                }
            }

            #pragma unroll
            for (int reg = 0; reg < 4; ++reg) {
                int r = row0 + quad * 4 + reg;
                if (r < N) {
                    #pragma unroll
                    for (int nt = 0; nt < 8; ++nt) {
                        sup[(size_t)r * D + nt * 16 + col] = f32_to_bf16(acc[nt][reg]);
                    }
                }
            }
        }
    }

    grid_barrier(bar + 1, nblk);

    // ---------------- Phase 2: SpMM (XCD feature-half, 8-deep gathers) ----
    {
        const int wave = tid >> 6;
        const int lane = tid & 63;
        const int eg   = lane >> 3;           // edge-group (0..7)
        const int fl   = lane & 7;            // feature octet owner (0..7)

        const int nblk_half = (N + 3) / 4;
        const int nvb = ((nblk_half + 3) / 4) * 8;

        for (int vb = blockIdx.x; vb < nvb; vb += nblk) {
            const int xcd  = vb & 7;
            const int half = xcd >> 2;                   // 0: feats 0-63, 1: 64-127
            const int grp  = (vb >> 3) * 4 + (xcd & 3);
            const int node = grp * 4 + wave;
            if (node >= N) continue;

            const int start = rp[node];
            const int end   = rp[node + 1];

            const unsigned off = (unsigned)half * 64u + (unsigned)fl * 8u;  // u16 units

            float acc[8];
            #pragma unroll
            for (int j = 0; j < 8; ++j) acc[j] = 0.f;

            for (int base = start; base < end; base += 64) {
                int cnt = end - base;
                if (cnt > 64) cnt = 64;

                int mi = base + lane;
                int   sv = (mi < end) ? esrc[mi] : 0;
                float wv = (mi < end) ? ew[mi]   : 0.f;

                uint4 u[8];
                float w[8];
                #pragma unroll
                for (int g = 0; g < 8; ++g) {
                    int idx  = g * 8 + eg;
                    int cidx = (idx < cnt) ? idx : (cnt - 1);
                    int   s  = __shfl(sv, cidx);
                    float wt = __shfl(wv, cidx);
                    w[g] = (idx < cnt) ? wt : 0.f;
                    u[g] = *(const uint4*)(sup + (size_t)s * D + off);
                }
                #pragma unroll
                for (int g = 0; g < 8; ++g) {
                    unsigned d0 = u[g].x, d1 = u[g].y, d2 = u[g].z, d3 = u[g].w;
                    acc[0] = fmaf(w[g], __uint_as_float(d0 << 16),         acc[0]);
                    acc[1] = fmaf(w[g], __uint_as_float(d0 & 0xffff0000u), acc[1]);
                    acc[2] = fmaf(w[g], __uint_as_float(d1 << 16),         acc[2]);
                    acc[3] = fmaf(w[g], __uint_as_float(d1 & 0xffff0000u), acc[3]);
                    acc[4] = fmaf(w[g], __uint_as_float(d2 << 16),         acc[4]);
                    acc[5] = fmaf(w[g], __uint_as_float(d2 & 0xffff0000u), acc[5]);
                    acc[6] = fmaf(w[g], __uint_as_float(d3 << 16),         acc[6]);
                    acc[7] = fmaf(w[g], __uint_as_float(d3 & 0xffff0000u), acc[7]);
                }
            }

            // Reduce across the 8 edge-groups (lanes sharing fl).
            #pragma unroll
            for (int m = 8; m <= 32; m <<= 1) {
                #pragma unroll
                for (int j = 0; j < 8; ++j) acc[j] += __shfl_xor(acc[j], m);
            }

            if (eg == 0) {
                float* dst = out + (size_t)node * D + off;
                float4 o0 = make_float4(acc[0], acc[1], acc[2], acc[3]);
                float4 o1 = make_float4(acc[4], acc[5], acc[6], acc[7]);
                *(float4*)dst       = o0;
                *(float4*)(dst + 4) = o1;
            }
        }
    }
}

extern "C" void kernel_launch(void* const* d_in, const int* in_sizes, int n_in,
                              void* d_out, int out_size, void* d_ws, size_t ws_size,
                              hipStream_t stream) {
    const float* x    = (const float*)d_in[0];
    const float* W    = (const float*)d_in[1];
    const float* b    = (const float*)d_in[2];
    const float* ew   = (const float*)d_in[3];
    const int*   esrc = (const int*)d_in[4];
    const int*   edst = (const int*)d_in[5];
    float* out = (float*)d_out;

    int N = in_sizes[0] / D;
    int E = in_sizes[3];

    u16* sup = (u16*)d_ws;                                        // N*128 bf16
    int* rp  = (int*)((char*)d_ws + (size_t)N * D * sizeof(u16)); // N+1 ints
    u16* Wt  = (u16*)((char*)rp + ((size_t)N + 16) * sizeof(int));// 128*128 bf16
    int* bar = (int*)((char*)Wt + (size_t)128 * 128 * sizeof(u16)); // 2 ints

    hipMemsetAsync(bar, 0, 2 * sizeof(int), stream);

    hipLaunchKernelGGL(fused_kernel, dim3(512), dim3(256), 0, stream,
                       x, W, b, ew, esrc, edst, out, sup, rp, Wt, bar, N, E);
}

// Round 6
// 240.241 us; speedup vs baseline: 1.8528x; 1.8097x over previous
//
#include <hip/hip_runtime.h>

#define D 128
#define WS 136   // padded LDS row stride (bf16 units): bank = 68*n mod 32 -> 8 banks

typedef unsigned short u16;
typedef unsigned int   u32;
typedef __attribute__((ext_vector_type(8))) short bf16x8;
typedef __attribute__((ext_vector_type(4))) float f32x4;

__device__ __forceinline__ u16 f32_to_bf16(float f) {
    unsigned u = __float_as_uint(f);
    unsigned rounding = 0x7fffu + ((u >> 16) & 1u);   // round-to-nearest-even
    return (u16)((u + rounding) >> 16);
}

__device__ __forceinline__ float bf16_to_f32(u16 s) {
    return __uint_as_float(((unsigned)s) << 16);
}

// -------------------------------------------------------------------------
// Kernel 1 (FUSED): per-block LDS staging of W^T (replaces prep kernel +
// its grid-level dependency with a block-local __syncthreads), then the
// proven MFMA gemm body, then rowptr grid-strided. No grid barrier, no
// co-residency requirement: full occupancy, oversubscribed grid.
// -------------------------------------------------------------------------
__global__ __launch_bounds__(256) void gemm_rowptr_kernel(
    const float* __restrict__ x, const float* __restrict__ W,
    const float* __restrict__ b, const int* __restrict__ edst,
    u16* __restrict__ sup, int* __restrict__ rp, int N, int E)
{
    __shared__ u16 Wt_lds[128 * WS];   // Wt_lds[n*WS + k] = bf16(W[k][n]), 34 KB

    const int tid = threadIdx.x;

    // ---- stage W -> LDS transposed (each thread: 64 elements) ----
    #pragma unroll
    for (int i = 0; i < 64; ++i) {
        int idx = i * 256 + tid;        // idx = k*128 + n
        int k = idx >> 7;
        int n = idx & 127;
        Wt_lds[n * WS + k] = f32_to_bf16(W[idx]);
    }
    __syncthreads();

    // ---- GEMM: support = bf16(x @ W + b) ----
    {
        const int lane = tid & 63;
        const int wave = tid >> 6;
        const int col  = lane & 15;
        const int quad = lane >> 4;
        const int row0 = blockIdx.x * 64 + wave * 16;
        const int m    = row0 + col;
        const bool mvalid = (m < N);

        f32x4 acc[8];
        #pragma unroll
        for (int nt = 0; nt < 8; ++nt) {
            float bias = b[nt * 16 + col];
            acc[nt][0] = bias; acc[nt][1] = bias;
            acc[nt][2] = bias; acc[nt][3] = bias;
        }

        const float* xrow = x + (size_t)m * D;

        #pragma unroll
        for (int ks = 0; ks < 4; ++ks) {
            const int k0 = ks * 32 + quad * 8;

            float af[8];
            if (mvalid) {
                float4 v0 = *(const float4*)(xrow + k0);
                float4 v1 = *(const float4*)(xrow + k0 + 4);
                af[0] = v0.x; af[1] = v0.y; af[2] = v0.z; af[3] = v0.w;
                af[4] = v1.x; af[5] = v1.y; af[6] = v1.z; af[7] = v1.w;
            } else {
                #pragma unroll
                for (int j = 0; j < 8; ++j) af[j] = 0.f;
            }

            bf16x8 ahi, alo;
            #pragma unroll
            for (int j = 0; j < 8; ++j) {
                u16 h = f32_to_bf16(af[j]);
                float r = af[j] - bf16_to_f32(h);
                ahi[j] = (short)h;
                alo[j] = (short)f32_to_bf16(r);
            }

            #pragma unroll
            for (int nt = 0; nt < 8; ++nt) {
                bf16x8 bfrag = *(const bf16x8*)(&Wt_lds[(nt * 16 + col) * WS + k0]);
                acc[nt] = __builtin_amdgcn_mfma_f32_16x16x32_bf16(alo, bfrag, acc[nt], 0, 0, 0);
                acc[nt] = __builtin_amdgcn_mfma_f32_16x16x32_bf16(ahi, bfrag, acc[nt], 0, 0, 0);
            }
        }

        #pragma unroll
        for (int reg = 0; reg < 4; ++reg) {
            int r = row0 + quad * 4 + reg;
            if (r < N) {
                #pragma unroll
                for (int nt = 0; nt < 8; ++nt) {
                    sup[(size_t)r * D + nt * 16 + col] = f32_to_bf16(acc[nt][reg]);
                }
            }
        }
    }

    // ---- rowptr: rp[n] = lower_bound(edge_dst, n), grid-strided ----
    {
        const int nvb = (E + 255) / 256;
        for (int vb = blockIdx.x; vb < nvb; vb += gridDim.x) {
            int e = vb * 256 + tid;
            if (e < E) {
                int d = edst[e];
                int prev = (e == 0) ? -1 : edst[e - 1];
                for (int n = prev + 1; n <= d; ++n) rp[n] = e;
                if (e == E - 1) {
                    for (int n = d + 1; n <= N; ++n) rp[n] = E;
                }
            }
        }
    }
}

// -------------------------------------------------------------------------
// Kernel 2: SpMM — bit-identical to the proven R0 kernel (103.6 us).
// XCD-partitioned by feature half, dwordx4 gathers, 74% occupancy.
// -------------------------------------------------------------------------
__global__ __launch_bounds__(256) void spmm_kernel(
    const u16* __restrict__ sup, const float* __restrict__ ew,
    const int* __restrict__ esrc, const int* __restrict__ rp,
    float* __restrict__ out, int N)
{
    const int b    = blockIdx.x;
    const int xcd  = b & 7;
    const int half = xcd >> 2;                   // 0: feats 0-63, 1: feats 64-127
    const int grp  = (b >> 3) * 4 + (xcd & 3);   // block group within the half
    const int wave = threadIdx.x >> 6;
    const int lane = threadIdx.x & 63;
    const int node = grp * 4 + wave;
    if (node >= N) return;

    const int start = rp[node];
    const int end   = rp[node + 1];

    const int eg = lane >> 3;                    // edge-group within an iter
    const int fl = lane & 7;                     // feature octet owner
    const unsigned off = (unsigned)half * 64u + (unsigned)fl * 8u;  // u16 units

    float acc[8];
    #pragma unroll
    for (int j = 0; j < 8; ++j) acc[j] = 0.f;

    for (int base = start; base < end; base += 64) {
        int cnt = end - base;
        if (cnt > 64) cnt = 64;

        int mi = base + lane;
        int   sv = (mi < end) ? esrc[mi] : 0;
        float wv = (mi < end) ? ew[mi]   : 0.f;

        for (int i = 0; i < cnt; i += 32) {
            uint4 u[4];
            float w[4];
            #pragma unroll
            for (int g = 0; g < 4; ++g) {
                int idx  = i + g * 8 + eg;
                int cidx = (idx < cnt) ? idx : (cnt - 1);
                int   s  = __shfl(sv, cidx);
                float wt = __shfl(wv, cidx);
                w[g] = (idx < cnt) ? wt : 0.f;
                u[g] = *(const uint4*)(sup + (size_t)s * D + off);
            }
            #pragma unroll
            for (int g = 0; g < 4; ++g) {
                unsigned d0 = u[g].x, d1 = u[g].y, d2 = u[g].z, d3 = u[g].w;
                acc[0] = fmaf(w[g], __uint_as_float(d0 << 16),         acc[0]);
                acc[1] = fmaf(w[g], __uint_as_float(d0 & 0xffff0000u), acc[1]);
                acc[2] = fmaf(w[g], __uint_as_float(d1 << 16),         acc[2]);
                acc[3] = fmaf(w[g], __uint_as_float(d1 & 0xffff0000u), acc[3]);
                acc[4] = fmaf(w[g], __uint_as_float(d2 << 16),         acc[4]);
                acc[5] = fmaf(w[g], __uint_as_float(d2 & 0xffff0000u), acc[5]);
                acc[6] = fmaf(w[g], __uint_as_float(d3 << 16),         acc[6]);
                acc[7] = fmaf(w[g], __uint_as_float(d3 & 0xffff0000u), acc[7]);
            }
        }
    }

    // Reduce across the 8 edge-groups (lanes sharing fl).
    #pragma unroll
    for (int m = 8; m <= 32; m <<= 1) {
        #pragma unroll
        for (int j = 0; j < 8; ++j) acc[j] += __shfl_xor(acc[j], m);
    }

    if (eg == 0) {
        float* dst = out + (size_t)node * D + off;
        float4 o0 = make_float4(acc[0], acc[1], acc[2], acc[3]);
        float4 o1 = make_float4(acc[4], acc[5], acc[6], acc[7]);
        *(float4*)dst       = o0;
        *(float4*)(dst + 4) = o1;
    }
}

extern "C" void kernel_launch(void* const* d_in, const int* in_sizes, int n_in,
                              void* d_out, int out_size, void* d_ws, size_t ws_size,
                              hipStream_t stream) {
    const float* x    = (const float*)d_in[0];
    const float* W    = (const float*)d_in[1];
    const float* b    = (const float*)d_in[2];
    const float* ew   = (const float*)d_in[3];
    const int*   esrc = (const int*)d_in[4];
    const int*   edst = (const int*)d_in[5];
    float* out = (float*)d_out;

    const int N = in_sizes[0] / D;
    const int E = in_sizes[3];

    u16* sup = (u16*)d_ws;                                        // N*128 bf16
    int* rp  = (int*)((char*)d_ws + (size_t)N * D * sizeof(u16)); // N+1 ints

    hipLaunchKernelGGL(gemm_rowptr_kernel, dim3((N + 63) / 64), dim3(256), 0, stream,
                       x, W, b, edst, sup, rp, N, E);

    int nblk_half = (N + 3) / 4;
    int grid_spmm = ((nblk_half + 3) / 4) * 8;
    hipLaunchKernelGGL(spmm_kernel, dim3(grid_spmm), dim3(256), 0, stream,
                       sup, ew, esrc, rp, out, N);
}